// Round 19
// baseline (281.958 us; speedup 1.0000x reference)
//
#include <hip/hip_runtime.h>

#define DD 50176          // h*w
#define NB 16             // batches
#define NK 64             // k masks

constexpr int RS = 40;    // LDS row stride in bf16 (32 data + 8 pad, 80B: 16B-aligned)

using f32x4  = __attribute__((ext_vector_type(4))) float;
using bf16x8 = __attribute__((ext_vector_type(8))) short;   // 8 bf16 (4 VGPRs)

__device__ __forceinline__ ushort f2bf(float x) {           // fp32 -> bf16 RNE
  unsigned u = __float_as_uint(x);
  u += 0x7FFFu + ((u >> 16) & 1u);
  return (ushort)(u >> 16);
}
__device__ __forceinline__ float bf2f(ushort h) {
  return __uint_as_float((unsigned)h << 16);
}

// ---------------------------------------------------------------------------
// Kernel 1: split-K partial GEMM on MATRIX CORES (split-bf16, 3-pass),
// r18-proven math (absmax 0). NEW (r19): KSPLIT=128 -> 1024 blocks, 40KB LDS
// -> exactly 4 blocks/CU = 2 waves/SIMD. r18 ran 1 wave/SIMD and was
// latency-STALLED (VALU 19.5%, Mfma 5%, ~75% idle) — unlike the fp32 path
// (issue-bound, 37% VALU), this kernel should scale with occupancy.
// KPS=392: 24 full 16-k subtiles + 8-k tail (kq>=2 lanes stage zero regs,
// exact no-op) + zero half-chunk. Norms fp32 from staging regs (unchanged).
// ---------------------------------------------------------------------------
template <int KSPLIT>
__global__ __launch_bounds__(128) void gemm_partial(const float* __restrict__ A,
                                                    const float* __restrict__ B,
                                                    float* __restrict__ ws) {
  constexpr int KPS    = DD / KSPLIT;
  constexpr int NSUB   = (KPS + 15) / 16;          // 16-k subtiles
  constexpr int TAILV  = KPS - (NSUB - 1) * 16;    // valid k in last subtile
  constexpr int NCHUNK = (NSUB + 1) / 2;           // 32-k MFMA chunks
  const int b = blockIdx.y;
  const int w = threadIdx.x >> 6;        // wave 0..1
  const int lane = threadIdx.x & 63;
  const int s = blockIdx.x * 2 + w;      // split 0..KSPLIT-1
  const float* Ab = A + (size_t)b * NK * DD;
  const float* Bb = B + (size_t)b * NK * DD;

  __shared__ short smem[2][2][2][64 * RS];  // [wave][A|B][hi|lo][row*RS+k] = 40KB
  short* Ahi = smem[w][0][0];
  short* Alo = smem[w][0][1];
  short* Bhi = smem[w][1][0];
  short* Blo = smem[w][1][1];

  const int kq = lane & 3;               // staging k-granule (4 floats)
  const int rr = lane >> 2;              // staging row-in-group 0..15
  const int lrow = lane & 15;            // fragment row/col within 16-block
  const int koff = (lane >> 4) * 8;      // fragment k-offset within chunk

  f32x4 acc[4][4];
#pragma unroll
  for (int m = 0; m < 4; ++m)
#pragma unroll
    for (int n = 0; n < 4; ++n) acc[m][n] = f32x4{0.f, 0.f, 0.f, 0.f};
  float a2p[4] = {0.f, 0.f, 0.f, 0.f};
  float b2p[4] = {0.f, 0.f, 0.f, 0.f};
  float4 avr[4], bvr[4];

  const int kbase = s * KPS;
  // prologue: load sub-tile 0 (always full: NSUB >= 2)
#pragma unroll
  for (int f = 0; f < 4; ++f) {
    const int row = f * 16 + rr;
    avr[f] = *reinterpret_cast<const float4*>(Ab + (size_t)row * DD + kbase + kq * 4);
    bvr[f] = *reinterpret_cast<const float4*>(Bb + (size_t)row * DD + kbase + kq * 4);
  }

  for (int c = 0; c < NCHUNK; ++c) {
    const int halves = (2 * c + 1 < NSUB) ? 2 : 1;
    for (int h = 0; h < halves; ++h) {
      // convert current staged regs -> hi/lo bf16, write to LDS half h
#pragma unroll
      for (int f = 0; f < 4; ++f) {
        const int row = f * 16 + rr;
        const int base = row * RS + h * 16 + kq * 4;
        const float4 av = avr[f], bv = bvr[f];
        const ushort ah0 = f2bf(av.x), ah1 = f2bf(av.y), ah2 = f2bf(av.z), ah3 = f2bf(av.w);
        const ushort al0 = f2bf(av.x - bf2f(ah0)), al1 = f2bf(av.y - bf2f(ah1));
        const ushort al2 = f2bf(av.z - bf2f(ah2)), al3 = f2bf(av.w - bf2f(ah3));
        const ushort bh0 = f2bf(bv.x), bh1 = f2bf(bv.y), bh2 = f2bf(bv.z), bh3 = f2bf(bv.w);
        const ushort bl0 = f2bf(bv.x - bf2f(bh0)), bl1 = f2bf(bv.y - bf2f(bh1));
        const ushort bl2 = f2bf(bv.z - bf2f(bh2)), bl3 = f2bf(bv.w - bf2f(bh3));
        *reinterpret_cast<short4*>(&Ahi[base]) = make_short4(ah0, ah1, ah2, ah3);
        *reinterpret_cast<short4*>(&Alo[base]) = make_short4(al0, al1, al2, al3);
        *reinterpret_cast<short4*>(&Bhi[base]) = make_short4(bh0, bh1, bh2, bh3);
        *reinterpret_cast<short4*>(&Blo[base]) = make_short4(bl0, bl1, bl2, bl3);
        a2p[f] = fmaf(av.x, av.x, a2p[f]); a2p[f] = fmaf(av.y, av.y, a2p[f]);
        a2p[f] = fmaf(av.z, av.z, a2p[f]); a2p[f] = fmaf(av.w, av.w, a2p[f]);
        b2p[f] = fmaf(bv.x, bv.x, b2p[f]); b2p[f] = fmaf(bv.y, bv.y, b2p[f]);
        b2p[f] = fmaf(bv.z, bv.z, b2p[f]); b2p[f] = fmaf(bv.w, bv.w, b2p[f]);
      }
      // T14: prefetch next sub-tile (tail subtile: kq past TAILV stages zeros)
      const int st = 2 * c + h + 1;
      if (st < NSUB) {
        const int k0 = kbase + st * 16;
        const bool full = (st < NSUB - 1) || (TAILV == 16);
        if (full || kq * 4 < TAILV) {
#pragma unroll
          for (int f = 0; f < 4; ++f) {
            const int row = f * 16 + rr;
            avr[f] = *reinterpret_cast<const float4*>(Ab + (size_t)row * DD + k0 + kq * 4);
            bvr[f] = *reinterpret_cast<const float4*>(Bb + (size_t)row * DD + k0 + kq * 4);
          }
        } else {
#pragma unroll
          for (int f = 0; f < 4; ++f) {
            avr[f] = make_float4(0.f, 0.f, 0.f, 0.f);
            bvr[f] = make_float4(0.f, 0.f, 0.f, 0.f);
          }
        }
      }
    }
    if (halves == 1) {
      // zero-fill half 1 (exact no-op contributions)
      const short4 z4 = make_short4(0, 0, 0, 0);
#pragma unroll
      for (int f = 0; f < 4; ++f) {
        const int base = (f * 16 + rr) * RS + 16 + kq * 4;
        *reinterpret_cast<short4*>(&Ahi[base]) = z4;
        *reinterpret_cast<short4*>(&Alo[base]) = z4;
        *reinterpret_cast<short4*>(&Bhi[base]) = z4;
        *reinterpret_cast<short4*>(&Blo[base]) = z4;
      }
    }
    // ---- MFMA over the 32-k chunk: 4x4 16x16 tiles x 3 passes
    bf16x8 bhf[4], blf[4];
#pragma unroll
    for (int n = 0; n < 4; ++n) {
      const int r = 16 * n + lrow;
      bhf[n] = *reinterpret_cast<const bf16x8*>(&Bhi[r * RS + koff]);
      blf[n] = *reinterpret_cast<const bf16x8*>(&Blo[r * RS + koff]);
    }
#pragma unroll
    for (int m = 0; m < 4; ++m) {
      const int r = 16 * m + lrow;
      const bf16x8 ahf = *reinterpret_cast<const bf16x8*>(&Ahi[r * RS + koff]);
      const bf16x8 alf = *reinterpret_cast<const bf16x8*>(&Alo[r * RS + koff]);
#pragma unroll
      for (int n = 0; n < 4; ++n) {
        acc[m][n] = __builtin_amdgcn_mfma_f32_16x16x32_bf16(ahf, bhf[n], acc[m][n], 0, 0, 0);
        acc[m][n] = __builtin_amdgcn_mfma_f32_16x16x32_bf16(ahf, blf[n], acc[m][n], 0, 0, 0);
        acc[m][n] = __builtin_amdgcn_mfma_f32_16x16x32_bf16(alf, bhf[n], acc[m][n], 0, 0, 0);
      }
    }
  }

  // ---- C write: D col=lane&15, row=(lane>>4)*4+reg (m89-verified)
  float* Pab = ws + (size_t)(b * KSPLIT + s) * 4096;
  const int drow0 = (lane >> 4) * 4;
#pragma unroll
  for (int m = 0; m < 4; ++m)
#pragma unroll
    for (int n = 0; n < 4; ++n) {
      const int col = 16 * n + lrow;
#pragma unroll
      for (int r = 0; r < 4; ++r)
        Pab[(16 * m + drow0 + r) * 64 + col] = acc[m][n][r];
    }

  // reduce norm partials across the 4 kq lanes of each row-group
#pragma unroll
  for (int f = 0; f < 4; ++f) {
    a2p[f] += __shfl_xor(a2p[f], 1, 64);
    a2p[f] += __shfl_xor(a2p[f], 2, 64);
    b2p[f] += __shfl_xor(b2p[f], 1, 64);
    b2p[f] += __shfl_xor(b2p[f], 2, 64);
  }
  if (kq == 0) {                         // 16 lanes, rr = 0..15
    float* Pa2 = ws + (size_t)NB * KSPLIT * 4096 + (size_t)(b * KSPLIT + s) * 64;
    float* Pb2 = Pa2 + (size_t)NB * KSPLIT * 64;
#pragma unroll
    for (int f = 0; f < 4; ++f) {
      Pa2[f * 16 + rr] = a2p[f];
      Pb2[f * 16 + rr] = b2p[f];
    }
  }
}

// ---------------------------------------------------------------------------
// Kernel 2: parallel cost build. 16 slices x 16 batches = 256 blocks.
// Internal reduction in double; final cost cast to fp32 for the solver.
// ---------------------------------------------------------------------------
template <int NSPLIT>
__global__ __launch_bounds__(256) void reduce_cost(const float* __restrict__ ws,
                                                   float* __restrict__ costg) {
  const int slice = blockIdx.x;  // 0..15
  const int b = blockIdx.y;
  const int tid = threadIdx.x;
  __shared__ double a2s[4], b2s[64];
  const size_t pa2 = (size_t)NB * NSPLIT * 4096;
  const size_t pb2 = pa2 + (size_t)NB * NSPLIT * 64;

  if (tid < 64) {
    double s = 0.0;
    for (int sp = 0; sp < NSPLIT; ++sp)
      s += (double)ws[pb2 + (size_t)(b * NSPLIT + sp) * 64 + tid];
    b2s[tid] = s;
  } else if (tid < 68) {
    const int r = slice * 4 + (tid - 64);
    double s = 0.0;
    for (int sp = 0; sp < NSPLIT; ++sp)
      s += (double)ws[pa2 + (size_t)(b * NSPLIT + sp) * 64 + r];
    a2s[tid - 64] = s;
  }

  const int elem = slice * 256 + tid;   // 0..4095
  double acc = 0.0;
  for (int sp = 0; sp < NSPLIT; ++sp)
    acc += (double)ws[(size_t)(b * NSPLIT + sp) * 4096 + elem];
  __syncthreads();

  const int ii = tid >> 6;              // row within slice
  const int j = tid & 63;
  const double c2 = a2s[ii] + b2s[j] - 2.0 * acc;
  costg[(size_t)b * 4096 + elem] = (float)sqrt(c2 > 0.0 ? c2 : 0.0);
}

// ---------------------------------------------------------------------------
// Kernel 3: pure solver, fp32 (r10/r16 proven). 16 blocks x 1 wave.
// Col-reduction init + greedy, JV reduction transfer, ARR with fused
// min/2nd-min DPP reduce (cap 8, 2 passes), register Dijkstra.
// ---------------------------------------------------------------------------
__device__ __forceinline__ float readlane_f(float x, int lane) {
  return __int_as_float(__builtin_amdgcn_readlane(__float_as_int(x), lane));
}

template <int CTRL, int RMASK>
__device__ __forceinline__ float dpp_mov_inf(float k) {
  return __int_as_float(__builtin_amdgcn_update_dpp(
      0x7F800000, __float_as_int(k), CTRL, RMASK, 0xf, false));
}

template <int CTRL, int RMASK>
__device__ __forceinline__ float dpp_minf_step(float k) {
  return fminf(dpp_mov_inf<CTRL, RMASK>(k), k);
}
// 64-lane fp32 min, uniform result
__device__ __forceinline__ float dpp_minf(float k) {
  k = dpp_minf_step<0x111, 0xf>(k);   // row_shr:1
  k = dpp_minf_step<0x112, 0xf>(k);   // row_shr:2
  k = dpp_minf_step<0x114, 0xf>(k);   // row_shr:4
  k = dpp_minf_step<0x118, 0xf>(k);   // row_shr:8
  k = dpp_minf_step<0x142, 0xa>(k);   // row_bcast:15
  k = dpp_minf_step<0x143, 0xc>(k);   // row_bcast:31
  return readlane_f(k, 63);
}

template <int CTRL, int RMASK>
__device__ __forceinline__ void dpp_min2_step(float& m1, float& m2) {
  const float o1 = dpp_mov_inf<CTRL, RMASK>(m1);
  const float o2 = dpp_mov_inf<CTRL, RMASK>(m2);
  const float lo = fminf(m1, o1);
  const float hi = fmaxf(m1, o1);
  m2 = fminf(fminf(m2, o2), hi);
  m1 = lo;
}
// 64-lane fused (min, 2nd-min-multiset), uniform result
__device__ __forceinline__ float2 dpp_min2f(float x) {
  float m1 = x, m2 = __int_as_float(0x7F800000);
  dpp_min2_step<0x111, 0xf>(m1, m2);   // row_shr:1
  dpp_min2_step<0x112, 0xf>(m1, m2);   // row_shr:2
  dpp_min2_step<0x114, 0xf>(m1, m2);   // row_shr:4
  dpp_min2_step<0x118, 0xf>(m1, m2);   // row_shr:8
  dpp_min2_step<0x142, 0xa>(m1, m2);   // row_bcast:15
  dpp_min2_step<0x143, 0xc>(m1, m2);   // row_bcast:31
  return make_float2(readlane_f(m1, 63), readlane_f(m2, 63));
}

__global__ __launch_bounds__(64) void lsa_solve(const float* __restrict__ costg,
                                                int* __restrict__ out) {
  const int b = blockIdx.x;
  __shared__ float costd[64 * 64];
  const int tid = threadIdx.x;

  for (int e = tid; e < 4096; e += 64)
    costd[e] = costg[(size_t)b * 4096 + e];
  __syncthreads();

  const int l = tid;                 // lane l <-> column l+1, row l+1
  const float INFF = 1e30f;

  // ---- column reduction: v[j] = min_i c[i,j]; greedy tight matching, u=0
  float cmin = costd[l];
  int cargmin = 0;
#pragma unroll 8
  for (int r = 1; r < 64; ++r) {
    const float cv = costd[r * 64 + l];
    if (cv < cmin) { cmin = cv; cargmin = r; }
  }
  float v_l = cmin;
  float u_l = 0.0f;
  int p_l = 0;                       // row matched to column l+1 (0 = free)
  int colof_l = 0;                   // column matched to row l+1 (0 = free)
  unsigned long long rowused = 0ULL;
  for (int j = 0; j < 64; ++j) {
    const int rj = __builtin_amdgcn_readlane(cargmin, j);
    if (!((rowused >> rj) & 1ULL)) {
      rowused |= 1ULL << rj;
      if (l == j) p_l = rj + 1;
      if (l == rj) colof_l = j + 1;
    }
  }
  unsigned long long freemask = ~rowused;  // bit r-1 = row r unassigned

  // ---- JV reduction transfer
  {
    unsigned long long rm = rowused;
    while (rm) {
      const int ri = __ffsll(rm) - 1;          // 0-indexed matched row
      rm &= rm - 1;
      const int j1 = __builtin_amdgcn_readlane(colof_l, ri) - 1;  // its col
      const float red = (l == j1) ? INFF : (costd[ri * 64 + l] - v_l);
      const float rmin = dpp_minf(red);
      if (l == ri) u_l = rmin;
      if (l == j1) v_l -= rmin;
    }
  }

  // ---- Augmenting Row Reduction (JV), chain cap 8, 2 passes, fused 2-min
  for (int pass = 0; pass < 2; ++pass) {
    unsigned long long m = freemask;
    while (m) {
      int ir = __ffsll(m);           // 1-indexed free row
      m &= m - 1;
      for (int chain = 0; chain < 8; ++chain) {
        if (!((freemask >> (ir - 1)) & 1ULL)) break;
        const float uir = readlane_f(u_l, ir - 1);
        const float curx = costd[(ir - 1) * 64 + l] - uir - v_l;
        const float2 mm = dpp_min2f(curx);
        const float u1 = mm.x;
        const float u2 = mm.y;       // == min over j != j1 (incl. tie case)
        const int j1 = __ffsll(__ballot(curx == u1)) - 1;
        if (l == ir - 1) u_l = uir + u2;
        const bool strict = (u1 < u2);
        if (strict && l == j1) v_l -= (u2 - u1);
        const int k = __builtin_amdgcn_readlane(p_l, j1);  // occupant of col j1
        if (strict || k == 0) {
          if (l == j1) p_l = ir;
          if (l == ir - 1) colof_l = j1 + 1;
          freemask &= ~(1ULL << (ir - 1));
          if (k != 0) {
            if (l == k - 1) colof_l = 0;
            freemask |= 1ULL << (k - 1);
            if (strict) { ir = k; continue; }  // retry kicked row
          }
          break;
        } else {
          break;                     // tie & occupied: leave for Dijkstra
        }
      }
    }
  }

  // ---- shortest augmenting path for remaining free rows
  for (int i_row = 1; i_row <= 64; ++i_row) {
    if (!((freemask >> (i_row - 1)) & 1ULL)) continue;
    float minv = INFF;
    int way_l = 0;
    bool used = false;
    int j0 = 0;
    const bool irow_hit = (l + 1 == i_row);

    while (true) {
      const int i0 = (j0 == 0) ? i_row : __builtin_amdgcn_readlane(p_l, j0 - 1);
      if (i0 == 0) break;
      if (j0 > 0 && l == j0 - 1) used = true;
      // off the reduce chain: depends only on `used` and colof
      const unsigned long long um = __ballot(used);
      const bool addu = irow_hit ||
                        (colof_l != 0 && ((um >> (colof_l - 1)) & 1ULL));
      const float ui0 = readlane_f(u_l, i0 - 1);
      const float cur = costd[(i0 - 1) * 64 + l] - ui0 - v_l;
      if (!used && cur < minv) { minv = cur; way_l = j0; }
      const float cand = used ? INFF : minv;

      const float delta = dpp_minf(cand);
      const int jmin = __ffsll(__ballot(cand == delta)) - 1;

      if (used) v_l -= delta; else minv -= delta;
      if (addu) u_l += delta;
      j0 = jmin + 1;
    }

    while (j0 != 0) {
      const int j1 = __builtin_amdgcn_readlane(way_l, j0 - 1);
      const int pj1 = (j1 == 0) ? i_row : __builtin_amdgcn_readlane(p_l, j1 - 1);
      if (l == j0 - 1) p_l = pj1;
      if (l == pj1 - 1) colof_l = j0;
      j0 = j1;
    }
  }

  out[b * NK + l] = l;                       // inds  (arange)
  out[NB * NK + b * NK + l] = colof_l - 1;   // inds2 (col of row l+1)
}

extern "C" void kernel_launch(void* const* d_in, const int* in_sizes, int n_in,
                              void* d_out, int out_size, void* d_ws, size_t ws_size,
                              hipStream_t stream) {
  const float* A = (const float*)d_in[0];   // outputs [16,64,50176] fp32
  const float* B = (const float*)d_in[1];   // targets [16,64,50176] fp32
  float* ws = (float*)d_ws;
  int* out = (int*)d_out;                   // 2048 int32: [inds | inds2]

  // KSPLIT=128: partials NB*128*4224 floats ≈ 34.6 MB (+cost). r13-proven fit.
  const size_t f128 = (size_t)NB * 128 * 4224;
  const size_t need128 = (f128 + (size_t)NB * 4096) * 4;

  if (ws_size >= need128) {
    float* costg = ws + f128;
    gemm_partial<128><<<dim3(64, NB), 128, 0, stream>>>(A, B, ws);
    reduce_cost<128><<<dim3(16, NB), 256, 0, stream>>>(ws, costg);
    lsa_solve<<<NB, 64, 0, stream>>>(costg, out);
  } else {
    const size_t f64 = (size_t)NB * 64 * 4224;
    float* costg = ws + f64;
    gemm_partial<64><<<dim3(32, NB), 128, 0, stream>>>(A, B, ws);
    reduce_cost<64><<<dim3(16, NB), 256, 0, stream>>>(ws, costg);
    lsa_solve<<<NB, 64, 0, stream>>>(costg, out);
  }
}

// Round 20
// 270.068 us; speedup vs baseline: 1.0440x; 1.0440x over previous
//
#include <hip/hip_runtime.h>

#define DD 50176          // h*w
#define NB 16             // batches
#define NK 64             // k masks

constexpr int KSPLIT = 64;   // splits per batch (16 blocks x 4 waves)
constexpr int NPAIR  = 25;   // 32-k pairs per split (24 full + 1 half+zeros)
constexpr int TKK    = 32;   // kk per LDS tile

// ---------------------------------------------------------------------------
// Kernel 1: split-K partial GEMM, fp32 8x8 (r16 math, bit-identical FMA order
// per kk). NEW (r20): staging reads use 128-BYTE contiguous runs per 8 lanes
// (lane = rr8*8+kg8: row = f*8+rr8, k = k0+kg8*4) — full cache lines, vs the
// old 64B half-line runs that capped effective HBM BW at ~2.7 TB/s across all
// r10-r19 variants. TKK=32 (24 full pairs + 1 half staged with zero regs =
// exact no-op). Wave-private 16KB LDS slice (64KB/block, 1 block/CU at 256
// blocks — same distribution as r16). Skew col=(row+8*kg8)&63 on write,
// g=8*(kk>>2) on read: both <=2-way (r16 algebra).
// ---------------------------------------------------------------------------
__global__ __launch_bounds__(256) void gemm_partial(const float* __restrict__ A,
                                                    const float* __restrict__ B,
                                                    float* __restrict__ ws) {
  const int b = blockIdx.y;
  const int w = threadIdx.x >> 6;        // wave 0..3
  const int lane = threadIdx.x & 63;
  const int s = blockIdx.x * 4 + w;      // split 0..63
  const float* Ab = A + (size_t)b * NK * DD;
  const float* Bb = B + (size_t)b * NK * DD;

  __shared__ __align__(16) float lds[4][2][TKK * 64];  // [wave][A|B][kk][col] = 64KB
  float* As = lds[w][0];
  float* Bs = lds[w][1];

  const int ti = lane >> 3;              // output row-octet 0..7
  const int tj = lane & 7;               // output col-octet 0..7
  const int kg8 = lane & 7;              // staging k-granule 0..7 (16B each = 128B/row)
  const int rr8 = lane >> 3;             // staging row-in-octet 0..7

  float c[8][8];
#pragma unroll
  for (int r = 0; r < 8; ++r)
#pragma unroll
    for (int q = 0; q < 8; ++q) c[r][q] = 0.f;
  float a2p[8] = {0.f, 0.f, 0.f, 0.f, 0.f, 0.f, 0.f, 0.f};
  float b2p[8] = {0.f, 0.f, 0.f, 0.f, 0.f, 0.f, 0.f, 0.f};
  float4 avr[8], bvr[8];

  const int kbase = s * 784;             // KPS = 784
  // prologue: load pair 0 (full)
#pragma unroll
  for (int f = 0; f < 8; ++f) {
    const int row = f * 8 + rr8;
    avr[f] = *reinterpret_cast<const float4*>(Ab + (size_t)row * DD + kbase + kg8 * 4);
    bvr[f] = *reinterpret_cast<const float4*>(Bb + (size_t)row * DD + kbase + kg8 * 4);
  }

  for (int t = 0; t < NPAIR; ++t) {
    // stage regs -> LDS (transpose + skew); accumulate norms from regs
#pragma unroll
    for (int f = 0; f < 8; ++f) {
      const int row = f * 8 + rr8;
      const int col = (row + 8 * kg8) & 63;
      const float4 av = avr[f], bv = bvr[f];
      As[(kg8 * 4 + 0) * 64 + col] = av.x;
      As[(kg8 * 4 + 1) * 64 + col] = av.y;
      As[(kg8 * 4 + 2) * 64 + col] = av.z;
      As[(kg8 * 4 + 3) * 64 + col] = av.w;
      Bs[(kg8 * 4 + 0) * 64 + col] = bv.x;
      Bs[(kg8 * 4 + 1) * 64 + col] = bv.y;
      Bs[(kg8 * 4 + 2) * 64 + col] = bv.z;
      Bs[(kg8 * 4 + 3) * 64 + col] = bv.w;
      a2p[f] = fmaf(av.x, av.x, a2p[f]); a2p[f] = fmaf(av.y, av.y, a2p[f]);
      a2p[f] = fmaf(av.z, av.z, a2p[f]); a2p[f] = fmaf(av.w, av.w, a2p[f]);
      b2p[f] = fmaf(bv.x, bv.x, b2p[f]); b2p[f] = fmaf(bv.y, bv.y, b2p[f]);
      b2p[f] = fmaf(bv.z, bv.z, b2p[f]); b2p[f] = fmaf(bv.w, bv.w, b2p[f]);
    }
    // T14: issue next pair's loads; drain under this pair's compute.
    // Last pair (t=NPAIR-1 next): only 16 real k -> kg8>=4 lanes stage zeros.
    if (t + 1 < NPAIR) {
      const int k0 = kbase + (t + 1) * TKK;
      const bool full = (t + 1 < NPAIR - 1);
      if (full || kg8 * 4 < 16) {
#pragma unroll
        for (int f = 0; f < 8; ++f) {
          const int row = f * 8 + rr8;
          avr[f] = *reinterpret_cast<const float4*>(Ab + (size_t)row * DD + k0 + kg8 * 4);
          bvr[f] = *reinterpret_cast<const float4*>(Bb + (size_t)row * DD + k0 + kg8 * 4);
        }
      } else {
#pragma unroll
        for (int f = 0; f < 8; ++f) {
          avr[f] = make_float4(0.f, 0.f, 0.f, 0.f);
          bvr[f] = make_float4(0.f, 0.f, 0.f, 0.f);
        }
      }
    }
    // compute: 32 kk x 64 FMA per lane
#pragma unroll 4
    for (int kk = 0; kk < TKK; ++kk) {
      const int g = 8 * (kk >> 2);
      const float4 a0 = *reinterpret_cast<const float4*>(&As[kk * 64 + ((8 * ti + g) & 63)]);
      const float4 a1 = *reinterpret_cast<const float4*>(&As[kk * 64 + ((8 * ti + 4 + g) & 63)]);
      const float4 b0 = *reinterpret_cast<const float4*>(&Bs[kk * 64 + ((8 * tj + g) & 63)]);
      const float4 b1 = *reinterpret_cast<const float4*>(&Bs[kk * 64 + ((8 * tj + 4 + g) & 63)]);
      const float ar[8] = {a0.x, a0.y, a0.z, a0.w, a1.x, a1.y, a1.z, a1.w};
      const float br[8] = {b0.x, b0.y, b0.z, b0.w, b1.x, b1.y, b1.z, b1.w};
#pragma unroll
      for (int r = 0; r < 8; ++r)
#pragma unroll
        for (int q = 0; q < 8; ++q)
          c[r][q] = fmaf(ar[r], br[q], c[r][q]);
    }
  }

  float* Pab = ws + (size_t)(b * KSPLIT + s) * 4096;
#pragma unroll
  for (int r = 0; r < 8; ++r) {
    *reinterpret_cast<float4*>(Pab + (8 * ti + r) * 64 + 8 * tj) =
        make_float4(c[r][0], c[r][1], c[r][2], c[r][3]);
    *reinterpret_cast<float4*>(Pab + (8 * ti + r) * 64 + 8 * tj + 4) =
        make_float4(c[r][4], c[r][5], c[r][6], c[r][7]);
  }

  // reduce norm partials across the 8 kg8 lanes of each row-octet
#pragma unroll
  for (int f = 0; f < 8; ++f) {
    a2p[f] += __shfl_xor(a2p[f], 1, 64);
    a2p[f] += __shfl_xor(a2p[f], 2, 64);
    a2p[f] += __shfl_xor(a2p[f], 4, 64);
    b2p[f] += __shfl_xor(b2p[f], 1, 64);
    b2p[f] += __shfl_xor(b2p[f], 2, 64);
    b2p[f] += __shfl_xor(b2p[f], 4, 64);
  }
  if (kg8 == 0) {                        // 8 lanes, rr8 = 0..7
    float* Pa2 = ws + (size_t)NB * KSPLIT * 4096 + (size_t)(b * KSPLIT + s) * 64;
    float* Pb2 = Pa2 + (size_t)NB * KSPLIT * 64;
#pragma unroll
    for (int f = 0; f < 8; ++f) {
      Pa2[f * 8 + rr8] = a2p[f];
      Pb2[f * 8 + rr8] = b2p[f];
    }
  }
}

// ---------------------------------------------------------------------------
// Kernel 2: parallel cost build. 16 slices x 16 batches = 256 blocks.
// Internal reduction in double; final cost cast to fp32 for the solver.
// ---------------------------------------------------------------------------
template <int NSPLIT>
__global__ __launch_bounds__(256) void reduce_cost(const float* __restrict__ ws,
                                                   float* __restrict__ costg) {
  const int slice = blockIdx.x;  // 0..15
  const int b = blockIdx.y;
  const int tid = threadIdx.x;
  __shared__ double a2s[4], b2s[64];
  const size_t pa2 = (size_t)NB * NSPLIT * 4096;
  const size_t pb2 = pa2 + (size_t)NB * NSPLIT * 64;

  if (tid < 64) {
    double s = 0.0;
    for (int sp = 0; sp < NSPLIT; ++sp)
      s += (double)ws[pb2 + (size_t)(b * NSPLIT + sp) * 64 + tid];
    b2s[tid] = s;
  } else if (tid < 68) {
    const int r = slice * 4 + (tid - 64);
    double s = 0.0;
    for (int sp = 0; sp < NSPLIT; ++sp)
      s += (double)ws[pa2 + (size_t)(b * NSPLIT + sp) * 64 + r];
    a2s[tid - 64] = s;
  }

  const int elem = slice * 256 + tid;   // 0..4095
  double acc = 0.0;
  for (int sp = 0; sp < NSPLIT; ++sp)
    acc += (double)ws[(size_t)(b * NSPLIT + sp) * 4096 + elem];
  __syncthreads();

  const int ii = tid >> 6;              // row within slice
  const int j = tid & 63;
  const double c2 = a2s[ii] + b2s[j] - 2.0 * acc;
  costg[(size_t)b * 4096 + elem] = (float)sqrt(c2 > 0.0 ? c2 : 0.0);
}

// ---------------------------------------------------------------------------
// Kernel 3: pure solver, fp32 (r10/r16 proven). 16 blocks x 1 wave.
// Col-reduction init + greedy, JV reduction transfer, ARR with fused
// min/2nd-min DPP reduce (cap 8, 2 passes), register Dijkstra.
// ---------------------------------------------------------------------------
__device__ __forceinline__ float readlane_f(float x, int lane) {
  return __int_as_float(__builtin_amdgcn_readlane(__float_as_int(x), lane));
}

template <int CTRL, int RMASK>
__device__ __forceinline__ float dpp_mov_inf(float k) {
  return __int_as_float(__builtin_amdgcn_update_dpp(
      0x7F800000, __float_as_int(k), CTRL, RMASK, 0xf, false));
}

template <int CTRL, int RMASK>
__device__ __forceinline__ float dpp_minf_step(float k) {
  return fminf(dpp_mov_inf<CTRL, RMASK>(k), k);
}
// 64-lane fp32 min, uniform result
__device__ __forceinline__ float dpp_minf(float k) {
  k = dpp_minf_step<0x111, 0xf>(k);   // row_shr:1
  k = dpp_minf_step<0x112, 0xf>(k);   // row_shr:2
  k = dpp_minf_step<0x114, 0xf>(k);   // row_shr:4
  k = dpp_minf_step<0x118, 0xf>(k);   // row_shr:8
  k = dpp_minf_step<0x142, 0xa>(k);   // row_bcast:15
  k = dpp_minf_step<0x143, 0xc>(k);   // row_bcast:31
  return readlane_f(k, 63);
}

template <int CTRL, int RMASK>
__device__ __forceinline__ void dpp_min2_step(float& m1, float& m2) {
  const float o1 = dpp_mov_inf<CTRL, RMASK>(m1);
  const float o2 = dpp_mov_inf<CTRL, RMASK>(m2);
  const float lo = fminf(m1, o1);
  const float hi = fmaxf(m1, o1);
  m2 = fminf(fminf(m2, o2), hi);
  m1 = lo;
}
// 64-lane fused (min, 2nd-min-multiset), uniform result
__device__ __forceinline__ float2 dpp_min2f(float x) {
  float m1 = x, m2 = __int_as_float(0x7F800000);
  dpp_min2_step<0x111, 0xf>(m1, m2);   // row_shr:1
  dpp_min2_step<0x112, 0xf>(m1, m2);   // row_shr:2
  dpp_min2_step<0x114, 0xf>(m1, m2);   // row_shr:4
  dpp_min2_step<0x118, 0xf>(m1, m2);   // row_shr:8
  dpp_min2_step<0x142, 0xa>(m1, m2);   // row_bcast:15
  dpp_min2_step<0x143, 0xc>(m1, m2);   // row_bcast:31
  return make_float2(readlane_f(m1, 63), readlane_f(m2, 63));
}

__global__ __launch_bounds__(64) void lsa_solve(const float* __restrict__ costg,
                                                int* __restrict__ out) {
  const int b = blockIdx.x;
  __shared__ float costd[64 * 64];
  const int tid = threadIdx.x;

  for (int e = tid; e < 4096; e += 64)
    costd[e] = costg[(size_t)b * 4096 + e];
  __syncthreads();

  const int l = tid;                 // lane l <-> column l+1, row l+1
  const float INFF = 1e30f;

  // ---- column reduction: v[j] = min_i c[i,j]; greedy tight matching, u=0
  float cmin = costd[l];
  int cargmin = 0;
#pragma unroll 8
  for (int r = 1; r < 64; ++r) {
    const float cv = costd[r * 64 + l];
    if (cv < cmin) { cmin = cv; cargmin = r; }
  }
  float v_l = cmin;
  float u_l = 0.0f;
  int p_l = 0;                       // row matched to column l+1 (0 = free)
  int colof_l = 0;                   // column matched to row l+1 (0 = free)
  unsigned long long rowused = 0ULL;
  for (int j = 0; j < 64; ++j) {
    const int rj = __builtin_amdgcn_readlane(cargmin, j);
    if (!((rowused >> rj) & 1ULL)) {
      rowused |= 1ULL << rj;
      if (l == j) p_l = rj + 1;
      if (l == rj) colof_l = j + 1;
    }
  }
  unsigned long long freemask = ~rowused;  // bit r-1 = row r unassigned

  // ---- JV reduction transfer
  {
    unsigned long long rm = rowused;
    while (rm) {
      const int ri = __ffsll(rm) - 1;          // 0-indexed matched row
      rm &= rm - 1;
      const int j1 = __builtin_amdgcn_readlane(colof_l, ri) - 1;  // its col
      const float red = (l == j1) ? INFF : (costd[ri * 64 + l] - v_l);
      const float rmin = dpp_minf(red);
      if (l == ri) u_l = rmin;
      if (l == j1) v_l -= rmin;
    }
  }

  // ---- Augmenting Row Reduction (JV), chain cap 8, 2 passes, fused 2-min
  for (int pass = 0; pass < 2; ++pass) {
    unsigned long long m = freemask;
    while (m) {
      int ir = __ffsll(m);           // 1-indexed free row
      m &= m - 1;
      for (int chain = 0; chain < 8; ++chain) {
        if (!((freemask >> (ir - 1)) & 1ULL)) break;
        const float uir = readlane_f(u_l, ir - 1);
        const float curx = costd[(ir - 1) * 64 + l] - uir - v_l;
        const float2 mm = dpp_min2f(curx);
        const float u1 = mm.x;
        const float u2 = mm.y;       // == min over j != j1 (incl. tie case)
        const int j1 = __ffsll(__ballot(curx == u1)) - 1;
        if (l == ir - 1) u_l = uir + u2;
        const bool strict = (u1 < u2);
        if (strict && l == j1) v_l -= (u2 - u1);
        const int k = __builtin_amdgcn_readlane(p_l, j1);  // occupant of col j1
        if (strict || k == 0) {
          if (l == j1) p_l = ir;
          if (l == ir - 1) colof_l = j1 + 1;
          freemask &= ~(1ULL << (ir - 1));
          if (k != 0) {
            if (l == k - 1) colof_l = 0;
            freemask |= 1ULL << (k - 1);
            if (strict) { ir = k; continue; }  // retry kicked row
          }
          break;
        } else {
          break;                     // tie & occupied: leave for Dijkstra
        }
      }
    }
  }

  // ---- shortest augmenting path for remaining free rows
  for (int i_row = 1; i_row <= 64; ++i_row) {
    if (!((freemask >> (i_row - 1)) & 1ULL)) continue;
    float minv = INFF;
    int way_l = 0;
    bool used = false;
    int j0 = 0;
    const bool irow_hit = (l + 1 == i_row);

    while (true) {
      const int i0 = (j0 == 0) ? i_row : __builtin_amdgcn_readlane(p_l, j0 - 1);
      if (i0 == 0) break;
      if (j0 > 0 && l == j0 - 1) used = true;
      // off the reduce chain: depends only on `used` and colof
      const unsigned long long um = __ballot(used);
      const bool addu = irow_hit ||
                        (colof_l != 0 && ((um >> (colof_l - 1)) & 1ULL));
      const float ui0 = readlane_f(u_l, i0 - 1);
      const float cur = costd[(i0 - 1) * 64 + l] - ui0 - v_l;
      if (!used && cur < minv) { minv = cur; way_l = j0; }
      const float cand = used ? INFF : minv;

      const float delta = dpp_minf(cand);
      const int jmin = __ffsll(__ballot(cand == delta)) - 1;

      if (used) v_l -= delta; else minv -= delta;
      if (addu) u_l += delta;
      j0 = jmin + 1;
    }

    while (j0 != 0) {
      const int j1 = __builtin_amdgcn_readlane(way_l, j0 - 1);
      const int pj1 = (j1 == 0) ? i_row : __builtin_amdgcn_readlane(p_l, j1 - 1);
      if (l == j0 - 1) p_l = pj1;
      if (l == pj1 - 1) colof_l = j0;
      j0 = j1;
    }
  }

  out[b * NK + l] = l;                       // inds  (arange)
  out[NB * NK + b * NK + l] = colof_l - 1;   // inds2 (col of row l+1)
}

extern "C" void kernel_launch(void* const* d_in, const int* in_sizes, int n_in,
                              void* d_out, int out_size, void* d_ws, size_t ws_size,
                              hipStream_t stream) {
  const float* A = (const float*)d_in[0];   // outputs [16,64,50176] fp32
  const float* B = (const float*)d_in[1];   // targets [16,64,50176] fp32
  float* ws = (float*)d_ws;
  int* out = (int*)d_out;                   // 2048 int32: [inds | inds2]

  // partials: NB*KSPLIT*(4096+128) floats ≈ 17.3 MB; cost floats appended.
  const size_t fpart = (size_t)NB * KSPLIT * 4224;
  float* costg = ws + fpart;

  gemm_partial<<<dim3(16, NB), 256, 0, stream>>>(A, B, ws);
  reduce_cost<KSPLIT><<<dim3(16, NB), 256, 0, stream>>>(ws, costg);
  lsa_solve<<<NB, 64, 0, stream>>>(costg, out);
}

// Round 21
// 257.857 us; speedup vs baseline: 1.0935x; 1.0474x over previous
//
#include <hip/hip_runtime.h>

#define DD 50176          // h*w
#define NB 16             // batches
#define NK 64             // k masks

constexpr int KSPLIT = 64;   // splits per batch (16 blocks x 4 waves)
constexpr int KTILE  = 49;   // 16-wide k-tiles per split (49*16=784; 64*784=50176)
constexpr int TKK    = 16;   // kk per tile

// ---------------------------------------------------------------------------
// Kernel 1: split-K partial GEMM — banked best (r16, 151us). 4 independent
// waves/block, wave-private k-slice + wave-private 8KB LDS (no __syncthreads).
// 8x8 register tile/lane. T14 register double-buffer; norms from staging regs.
// LDS transposed [kk][col], skew col=(row+8*(kk>>2))&63 (conflicts=0).
// Grid 16x16 = 256 blocks (KSPLIT=64 preserves L3 replay retention: FETCH
// ~209MB of 411MB). r12-r20 falsified: occupancy (2-4 w/SIMD), MFMA-convert,
// frag pipelining, 128B-run staging — all land 150-170us. This is the plateau
// for the staged-transpose structure.
// ---------------------------------------------------------------------------
__global__ __launch_bounds__(256) void gemm_partial(const float* __restrict__ A,
                                                    const float* __restrict__ B,
                                                    float* __restrict__ ws) {
  const int b = blockIdx.y;
  const int w = threadIdx.x >> 6;        // wave 0..3
  const int lane = threadIdx.x & 63;
  const int s = blockIdx.x * 4 + w;      // split 0..63
  const float* Ab = A + (size_t)b * NK * DD;
  const float* Bb = B + (size_t)b * NK * DD;

  __shared__ __align__(16) float lds[4][2][TKK * 64];  // [wave][A|B][kk][col]
  float* As = lds[w][0];
  float* Bs = lds[w][1];

  const int ti = lane >> 3;              // output row-octet 0..7
  const int tj = lane & 7;               // output col-octet 0..7
  const int kq = lane & 3;               // staging k-granule (4 floats)
  const int rr = lane >> 2;              // staging row-in-group 0..15

  float c[8][8];
#pragma unroll
  for (int r = 0; r < 8; ++r)
#pragma unroll
    for (int q = 0; q < 8; ++q) c[r][q] = 0.f;
  float a2p[4] = {0.f, 0.f, 0.f, 0.f};
  float b2p[4] = {0.f, 0.f, 0.f, 0.f};
  float4 avr[4], bvr[4];

  const int kbase = s * (KTILE * TKK);
  // prologue: load tile 0 into registers
#pragma unroll
  for (int f = 0; f < 4; ++f) {
    const int row = f * 16 + rr;
    avr[f] = *reinterpret_cast<const float4*>(Ab + (size_t)row * DD + kbase + kq * 4);
    bvr[f] = *reinterpret_cast<const float4*>(Bb + (size_t)row * DD + kbase + kq * 4);
  }

  for (int t = 0; t < KTILE; ++t) {
    // stage regs -> LDS (transpose + skew); accumulate norms from regs
#pragma unroll
    for (int f = 0; f < 4; ++f) {
      const int row = f * 16 + rr;
      const int col = (row + 8 * kq) & 63;
      const float4 av = avr[f], bv = bvr[f];
      As[(kq * 4 + 0) * 64 + col] = av.x;
      As[(kq * 4 + 1) * 64 + col] = av.y;
      As[(kq * 4 + 2) * 64 + col] = av.z;
      As[(kq * 4 + 3) * 64 + col] = av.w;
      Bs[(kq * 4 + 0) * 64 + col] = bv.x;
      Bs[(kq * 4 + 1) * 64 + col] = bv.y;
      Bs[(kq * 4 + 2) * 64 + col] = bv.z;
      Bs[(kq * 4 + 3) * 64 + col] = bv.w;
      a2p[f] = fmaf(av.x, av.x, a2p[f]); a2p[f] = fmaf(av.y, av.y, a2p[f]);
      a2p[f] = fmaf(av.z, av.z, a2p[f]); a2p[f] = fmaf(av.w, av.w, a2p[f]);
      b2p[f] = fmaf(bv.x, bv.x, b2p[f]); b2p[f] = fmaf(bv.y, bv.y, b2p[f]);
      b2p[f] = fmaf(bv.z, bv.z, b2p[f]); b2p[f] = fmaf(bv.w, bv.w, b2p[f]);
    }
    // T14: issue next tile's global loads; drain under this tile's compute
    if (t + 1 < KTILE) {
      const int k0 = kbase + (t + 1) * TKK;
#pragma unroll
      for (int f = 0; f < 4; ++f) {
        const int row = f * 16 + rr;
        avr[f] = *reinterpret_cast<const float4*>(Ab + (size_t)row * DD + k0 + kq * 4);
        bvr[f] = *reinterpret_cast<const float4*>(Bb + (size_t)row * DD + k0 + kq * 4);
      }
    }
    // compute: 16 kk x 64 FMA per lane
#pragma unroll 4
    for (int kk = 0; kk < TKK; ++kk) {
      const int g = 8 * (kk >> 2);
      const float4 a0 = *reinterpret_cast<const float4*>(&As[kk * 64 + ((8 * ti + g) & 63)]);
      const float4 a1 = *reinterpret_cast<const float4*>(&As[kk * 64 + ((8 * ti + 4 + g) & 63)]);
      const float4 b0 = *reinterpret_cast<const float4*>(&Bs[kk * 64 + ((8 * tj + g) & 63)]);
      const float4 b1 = *reinterpret_cast<const float4*>(&Bs[kk * 64 + ((8 * tj + 4 + g) & 63)]);
      const float ar[8] = {a0.x, a0.y, a0.z, a0.w, a1.x, a1.y, a1.z, a1.w};
      const float br[8] = {b0.x, b0.y, b0.z, b0.w, b1.x, b1.y, b1.z, b1.w};
#pragma unroll
      for (int r = 0; r < 8; ++r)
#pragma unroll
        for (int q = 0; q < 8; ++q)
          c[r][q] = fmaf(ar[r], br[q], c[r][q]);
    }
  }

  float* Pab = ws + (size_t)(b * KSPLIT + s) * 4096;
#pragma unroll
  for (int r = 0; r < 8; ++r) {
    *reinterpret_cast<float4*>(Pab + (8 * ti + r) * 64 + 8 * tj) =
        make_float4(c[r][0], c[r][1], c[r][2], c[r][3]);
    *reinterpret_cast<float4*>(Pab + (8 * ti + r) * 64 + 8 * tj + 4) =
        make_float4(c[r][4], c[r][5], c[r][6], c[r][7]);
  }

  // reduce norm partials across the 4 kq lanes of each row-group
#pragma unroll
  for (int f = 0; f < 4; ++f) {
    a2p[f] += __shfl_xor(a2p[f], 1, 64);
    a2p[f] += __shfl_xor(a2p[f], 2, 64);
    b2p[f] += __shfl_xor(b2p[f], 1, 64);
    b2p[f] += __shfl_xor(b2p[f], 2, 64);
  }
  if (kq == 0) {                         // 16 lanes, rr = 0..15
    float* Pa2 = ws + (size_t)NB * KSPLIT * 4096 + (size_t)(b * KSPLIT + s) * 64;
    float* Pb2 = Pa2 + (size_t)NB * KSPLIT * 64;
#pragma unroll
    for (int f = 0; f < 4; ++f) {
      Pa2[f * 16 + rr] = a2p[f];
      Pb2[f * 16 + rr] = b2p[f];
    }
  }
}

// ---------------------------------------------------------------------------
// Kernel 2: parallel cost build. 16 slices x 16 batches = 256 blocks.
// Internal reduction in double; final cost cast to fp32 for the solver.
// ---------------------------------------------------------------------------
template <int NSPLIT>
__global__ __launch_bounds__(256) void reduce_cost(const float* __restrict__ ws,
                                                   float* __restrict__ costg) {
  const int slice = blockIdx.x;  // 0..15
  const int b = blockIdx.y;
  const int tid = threadIdx.x;
  __shared__ double a2s[4], b2s[64];
  const size_t pa2 = (size_t)NB * NSPLIT * 4096;
  const size_t pb2 = pa2 + (size_t)NB * NSPLIT * 64;

  if (tid < 64) {
    double s = 0.0;
    for (int sp = 0; sp < NSPLIT; ++sp)
      s += (double)ws[pb2 + (size_t)(b * NSPLIT + sp) * 64 + tid];
    b2s[tid] = s;
  } else if (tid < 68) {
    const int r = slice * 4 + (tid - 64);
    double s = 0.0;
    for (int sp = 0; sp < NSPLIT; ++sp)
      s += (double)ws[pa2 + (size_t)(b * NSPLIT + sp) * 64 + r];
    a2s[tid - 64] = s;
  }

  const int elem = slice * 256 + tid;   // 0..4095
  double acc = 0.0;
  for (int sp = 0; sp < NSPLIT; ++sp)
    acc += (double)ws[(size_t)(b * NSPLIT + sp) * 4096 + elem];
  __syncthreads();

  const int ii = tid >> 6;              // row within slice
  const int j = tid & 63;
  const double c2 = a2s[ii] + b2s[j] - 2.0 * acc;
  costg[(size_t)b * 4096 + elem] = (float)sqrt(c2 > 0.0 ? c2 : 0.0);
}

// ---------------------------------------------------------------------------
// Kernel 3: pure solver, fp32 (r10/r16 proven). 16 blocks x 1 wave.
// Col-reduction init + greedy, JV reduction transfer, ARR with fused
// min/2nd-min DPP reduce (cap 8, 2 passes), register Dijkstra.
// ---------------------------------------------------------------------------
__device__ __forceinline__ float readlane_f(float x, int lane) {
  return __int_as_float(__builtin_amdgcn_readlane(__float_as_int(x), lane));
}

template <int CTRL, int RMASK>
__device__ __forceinline__ float dpp_mov_inf(float k) {
  // invalid lanes read old = +inf (min identity)
  return __int_as_float(__builtin_amdgcn_update_dpp(
      0x7F800000, __float_as_int(k), CTRL, RMASK, 0xf, false));
}

template <int CTRL, int RMASK>
__device__ __forceinline__ float dpp_minf_step(float k) {
  return fminf(dpp_mov_inf<CTRL, RMASK>(k), k);
}
// 64-lane fp32 min, uniform result
__device__ __forceinline__ float dpp_minf(float k) {
  k = dpp_minf_step<0x111, 0xf>(k);   // row_shr:1
  k = dpp_minf_step<0x112, 0xf>(k);   // row_shr:2
  k = dpp_minf_step<0x114, 0xf>(k);   // row_shr:4
  k = dpp_minf_step<0x118, 0xf>(k);   // row_shr:8
  k = dpp_minf_step<0x142, 0xa>(k);   // row_bcast:15
  k = dpp_minf_step<0x143, 0xc>(k);   // row_bcast:31
  return readlane_f(k, 63);
}

template <int CTRL, int RMASK>
__device__ __forceinline__ void dpp_min2_step(float& m1, float& m2) {
  const float o1 = dpp_mov_inf<CTRL, RMASK>(m1);
  const float o2 = dpp_mov_inf<CTRL, RMASK>(m2);
  const float lo = fminf(m1, o1);
  const float hi = fmaxf(m1, o1);
  m2 = fminf(fminf(m2, o2), hi);
  m1 = lo;
}
// 64-lane fused (min, 2nd-min-multiset), uniform result
__device__ __forceinline__ float2 dpp_min2f(float x) {
  float m1 = x, m2 = __int_as_float(0x7F800000);
  dpp_min2_step<0x111, 0xf>(m1, m2);   // row_shr:1
  dpp_min2_step<0x112, 0xf>(m1, m2);   // row_shr:2
  dpp_min2_step<0x114, 0xf>(m1, m2);   // row_shr:4
  dpp_min2_step<0x118, 0xf>(m1, m2);   // row_shr:8
  dpp_min2_step<0x142, 0xa>(m1, m2);   // row_bcast:15
  dpp_min2_step<0x143, 0xc>(m1, m2);   // row_bcast:31
  return make_float2(readlane_f(m1, 63), readlane_f(m2, 63));
}

__global__ __launch_bounds__(64) void lsa_solve(const float* __restrict__ costg,
                                                int* __restrict__ out) {
  const int b = blockIdx.x;
  __shared__ float costd[64 * 64];
  const int tid = threadIdx.x;

  // vectorized cost fill: 16 x float4 per lane (coalesced 1KB/iter)
  {
    const float4* src = reinterpret_cast<const float4*>(costg + (size_t)b * 4096);
    float4* dst = reinterpret_cast<float4*>(costd);
    for (int e = tid; e < 1024; e += 64) dst[e] = src[e];
  }
  __syncthreads();

  const int l = tid;                 // lane l <-> column l+1, row l+1
  const float INFF = 1e30f;

  // ---- column reduction: v[j] = min_i c[i,j]; greedy tight matching, u=0
  float cmin = costd[l];
  int cargmin = 0;
#pragma unroll 8
  for (int r = 1; r < 64; ++r) {
    const float cv = costd[r * 64 + l];
    if (cv < cmin) { cmin = cv; cargmin = r; }
  }
  float v_l = cmin;
  float u_l = 0.0f;
  int p_l = 0;                       // row matched to column l+1 (0 = free)
  int colof_l = 0;                   // column matched to row l+1 (0 = free)
  unsigned long long rowused = 0ULL;
  for (int j = 0; j < 64; ++j) {
    const int rj = __builtin_amdgcn_readlane(cargmin, j);
    if (!((rowused >> rj) & 1ULL)) {
      rowused |= 1ULL << rj;
      if (l == j) p_l = rj + 1;
      if (l == rj) colof_l = j + 1;
    }
  }
  unsigned long long freemask = ~rowused;  // bit r-1 = row r unassigned

  // ---- JV reduction transfer
  {
    unsigned long long rm = rowused;
    while (rm) {
      const int ri = __ffsll(rm) - 1;          // 0-indexed matched row
      rm &= rm - 1;
      const int j1 = __builtin_amdgcn_readlane(colof_l, ri) - 1;  // its col
      const float red = (l == j1) ? INFF : (costd[ri * 64 + l] - v_l);
      const float rmin = dpp_minf(red);
      if (l == ri) u_l = rmin;
      if (l == j1) v_l -= rmin;
    }
  }

  // ---- Augmenting Row Reduction (JV), chain cap 8, 2 passes, fused 2-min
  for (int pass = 0; pass < 2; ++pass) {
    unsigned long long m = freemask;
    while (m) {
      int ir = __ffsll(m);           // 1-indexed free row
      m &= m - 1;
      for (int chain = 0; chain < 8; ++chain) {
        if (!((freemask >> (ir - 1)) & 1ULL)) break;
        const float uir = readlane_f(u_l, ir - 1);
        const float curx = costd[(ir - 1) * 64 + l] - uir - v_l;
        const float2 mm = dpp_min2f(curx);
        const float u1 = mm.x;
        const float u2 = mm.y;       // == min over j != j1 (incl. tie case)
        const int j1 = __ffsll(__ballot(curx == u1)) - 1;
        if (l == ir - 1) u_l = uir + u2;
        const bool strict = (u1 < u2);
        if (strict && l == j1) v_l -= (u2 - u1);
        const int k = __builtin_amdgcn_readlane(p_l, j1);  // occupant of col j1
        if (strict || k == 0) {
          if (l == j1) p_l = ir;
          if (l == ir - 1) colof_l = j1 + 1;
          freemask &= ~(1ULL << (ir - 1));
          if (k != 0) {
            if (l == k - 1) colof_l = 0;
            freemask |= 1ULL << (k - 1);
            if (strict) { ir = k; continue; }  // retry kicked row
          }
          break;
        } else {
          break;                     // tie & occupied: leave for Dijkstra
        }
      }
    }
  }

  // ---- shortest augmenting path for remaining free rows
  for (int i_row = 1; i_row <= 64; ++i_row) {
    if (!((freemask >> (i_row - 1)) & 1ULL)) continue;
    float minv = INFF;
    int way_l = 0;
    bool used = false;
    int j0 = 0;
    const bool irow_hit = (l + 1 == i_row);

    while (true) {
      const int i0 = (j0 == 0) ? i_row : __builtin_amdgcn_readlane(p_l, j0 - 1);
      if (i0 == 0) break;
      if (j0 > 0 && l == j0 - 1) used = true;
      // off the reduce chain: depends only on `used` and colof
      const unsigned long long um = __ballot(used);
      const bool addu = irow_hit ||
                        (colof_l != 0 && ((um >> (colof_l - 1)) & 1ULL));
      const float ui0 = readlane_f(u_l, i0 - 1);
      const float cur = costd[(i0 - 1) * 64 + l] - ui0 - v_l;
      if (!used && cur < minv) { minv = cur; way_l = j0; }
      const float cand = used ? INFF : minv;

      const float delta = dpp_minf(cand);
      const int jmin = __ffsll(__ballot(cand == delta)) - 1;

      if (used) v_l -= delta; else minv -= delta;
      if (addu) u_l += delta;
      j0 = jmin + 1;
    }

    while (j0 != 0) {
      const int j1 = __builtin_amdgcn_readlane(way_l, j0 - 1);
      const int pj1 = (j1 == 0) ? i_row : __builtin_amdgcn_readlane(p_l, j1 - 1);
      if (l == j0 - 1) p_l = pj1;
      if (l == pj1 - 1) colof_l = j0;
      j0 = j1;
    }
  }

  out[b * NK + l] = l;                       // inds  (arange)
  out[NB * NK + b * NK + l] = colof_l - 1;   // inds2 (col of row l+1)
}

extern "C" void kernel_launch(void* const* d_in, const int* in_sizes, int n_in,
                              void* d_out, int out_size, void* d_ws, size_t ws_size,
                              hipStream_t stream) {
  const float* A = (const float*)d_in[0];   // outputs [16,64,50176] fp32
  const float* B = (const float*)d_in[1];   // targets [16,64,50176] fp32
  float* ws = (float*)d_ws;
  int* out = (int*)d_out;                   // 2048 int32: [inds | inds2]

  // partials: NB*KSPLIT*(4096+128) floats ≈ 17.3 MB; cost floats appended.
  const size_t fpart = (size_t)NB * KSPLIT * 4224;
  float* costg = ws + fpart;

  gemm_partial<<<dim3(16, NB), 256, 0, stream>>>(A, B, ws);
  reduce_cost<KSPLIT><<<dim3(16, NB), 256, 0, stream>>>(ws, costg);
  lsa_solve<<<NB, 64, 0, stream>>>(costg, out);
}

// Round 22
// 247.583 us; speedup vs baseline: 1.1388x; 1.0415x over previous
//
#include <hip/hip_runtime.h>

#define DD 50176          // h*w
#define NB 16             // batches
#define NK 64             // k masks

constexpr int KSPLIT = 64;   // splits per batch (16 blocks x 4 waves)
constexpr int KTILE  = 49;   // 16-wide k-tiles per split (49*16=784; 64*784=50176)
constexpr int TKK    = 16;   // kk per tile

// ---------------------------------------------------------------------------
// Kernel 1: split-K partial GEMM — r17 exact (best recorded: 248.1us total).
// 4 independent waves/block, wave-private k-slice + 8KB LDS (no syncs).
// 8x8 register tile/lane; T14 reg double-buffer; norms from staging regs;
// skew col=(row+8*(kk>>2))&63 (conflicts 0); 1-deep fragment pipeline.
// ---------------------------------------------------------------------------
__global__ __launch_bounds__(256) void gemm_partial(const float* __restrict__ A,
                                                    const float* __restrict__ B,
                                                    float* __restrict__ ws) {
  const int b = blockIdx.y;
  const int w = threadIdx.x >> 6;        // wave 0..3
  const int lane = threadIdx.x & 63;
  const int s = blockIdx.x * 4 + w;      // split 0..63
  const float* Ab = A + (size_t)b * NK * DD;
  const float* Bb = B + (size_t)b * NK * DD;

  __shared__ __align__(16) float lds[4][2][TKK * 64];  // [wave][A|B][kk][col]
  float* As = lds[w][0];
  float* Bs = lds[w][1];

  const int ti = lane >> 3;              // output row-octet 0..7
  const int tj = lane & 7;               // output col-octet 0..7
  const int kq = lane & 3;               // staging k-granule (4 floats)
  const int rr = lane >> 2;              // staging row-in-group 0..15

  float c[8][8];
#pragma unroll
  for (int r = 0; r < 8; ++r)
#pragma unroll
    for (int q = 0; q < 8; ++q) c[r][q] = 0.f;
  float a2p[4] = {0.f, 0.f, 0.f, 0.f};
  float b2p[4] = {0.f, 0.f, 0.f, 0.f};
  float4 avr[4], bvr[4];

  const int kbase = s * (KTILE * TKK);
  // prologue: load tile 0 into registers
#pragma unroll
  for (int f = 0; f < 4; ++f) {
    const int row = f * 16 + rr;
    avr[f] = *reinterpret_cast<const float4*>(Ab + (size_t)row * DD + kbase + kq * 4);
    bvr[f] = *reinterpret_cast<const float4*>(Bb + (size_t)row * DD + kbase + kq * 4);
  }

#define FRAG(da0, da1, db0, db1, KK)                                          \
  {                                                                           \
    const int g_ = 8 * ((KK) >> 2);                                           \
    da0 = *reinterpret_cast<const float4*>(&As[(KK) * 64 + ((8 * ti + g_) & 63)]);      \
    da1 = *reinterpret_cast<const float4*>(&As[(KK) * 64 + ((8 * ti + 4 + g_) & 63)]);  \
    db0 = *reinterpret_cast<const float4*>(&Bs[(KK) * 64 + ((8 * tj + g_) & 63)]);      \
    db1 = *reinterpret_cast<const float4*>(&Bs[(KK) * 64 + ((8 * tj + 4 + g_) & 63)]);  \
  }

  for (int t = 0; t < KTILE; ++t) {
    // stage regs -> LDS (transpose + skew); accumulate norms from regs
#pragma unroll
    for (int f = 0; f < 4; ++f) {
      const int row = f * 16 + rr;
      const int col = (row + 8 * kq) & 63;
      const float4 av = avr[f], bv = bvr[f];
      As[(kq * 4 + 0) * 64 + col] = av.x;
      As[(kq * 4 + 1) * 64 + col] = av.y;
      As[(kq * 4 + 2) * 64 + col] = av.z;
      As[(kq * 4 + 3) * 64 + col] = av.w;
      Bs[(kq * 4 + 0) * 64 + col] = bv.x;
      Bs[(kq * 4 + 1) * 64 + col] = bv.y;
      Bs[(kq * 4 + 2) * 64 + col] = bv.z;
      Bs[(kq * 4 + 3) * 64 + col] = bv.w;
      a2p[f] = fmaf(av.x, av.x, a2p[f]); a2p[f] = fmaf(av.y, av.y, a2p[f]);
      a2p[f] = fmaf(av.z, av.z, a2p[f]); a2p[f] = fmaf(av.w, av.w, a2p[f]);
      b2p[f] = fmaf(bv.x, bv.x, b2p[f]); b2p[f] = fmaf(bv.y, bv.y, b2p[f]);
      b2p[f] = fmaf(bv.z, bv.z, b2p[f]); b2p[f] = fmaf(bv.w, bv.w, b2p[f]);
    }
    // T14: issue next tile's global loads; drain under this tile's compute
    if (t + 1 < KTILE) {
      const int k0 = kbase + (t + 1) * TKK;
#pragma unroll
      for (int f = 0; f < 4; ++f) {
        const int row = f * 16 + rr;
        avr[f] = *reinterpret_cast<const float4*>(Ab + (size_t)row * DD + k0 + kq * 4);
        bvr[f] = *reinterpret_cast<const float4*>(Bb + (size_t)row * DD + k0 + kq * 4);
      }
    }
    // compute: 16 kk x 64 FMA per lane, 1-deep fragment pipeline
    {
      float4 a0c, a1c, b0c, b1c;
      float4 a0n, a1n, b0n, b1n;
      FRAG(a0c, a1c, b0c, b1c, 0);
#pragma unroll
      for (int kk = 0; kk < TKK; ++kk) {
        if (kk + 1 < TKK) FRAG(a0n, a1n, b0n, b1n, kk + 1);
        const float ar[8] = {a0c.x, a0c.y, a0c.z, a0c.w, a1c.x, a1c.y, a1c.z, a1c.w};
        const float br[8] = {b0c.x, b0c.y, b0c.z, b0c.w, b1c.x, b1c.y, b1c.z, b1c.w};
#pragma unroll
        for (int r = 0; r < 8; ++r)
#pragma unroll
          for (int q = 0; q < 8; ++q)
            c[r][q] = fmaf(ar[r], br[q], c[r][q]);
        if (kk + 1 < TKK) { a0c = a0n; a1c = a1n; b0c = b0n; b1c = b1n; }
      }
    }
  }
#undef FRAG

  float* Pab = ws + (size_t)(b * KSPLIT + s) * 4096;
#pragma unroll
  for (int r = 0; r < 8; ++r) {
    *reinterpret_cast<float4*>(Pab + (8 * ti + r) * 64 + 8 * tj) =
        make_float4(c[r][0], c[r][1], c[r][2], c[r][3]);
    *reinterpret_cast<float4*>(Pab + (8 * ti + r) * 64 + 8 * tj + 4) =
        make_float4(c[r][4], c[r][5], c[r][6], c[r][7]);
  }

  // reduce norm partials across the 4 kq lanes of each row-group
#pragma unroll
  for (int f = 0; f < 4; ++f) {
    a2p[f] += __shfl_xor(a2p[f], 1, 64);
    a2p[f] += __shfl_xor(a2p[f], 2, 64);
    b2p[f] += __shfl_xor(b2p[f], 1, 64);
    b2p[f] += __shfl_xor(b2p[f], 2, 64);
  }
  if (kq == 0) {                         // 16 lanes, rr = 0..15
    float* Pa2 = ws + (size_t)NB * KSPLIT * 4096 + (size_t)(b * KSPLIT + s) * 64;
    float* Pb2 = Pa2 + (size_t)NB * KSPLIT * 64;
#pragma unroll
    for (int f = 0; f < 4; ++f) {
      Pa2[f * 16 + rr] = a2p[f];
      Pb2[f * 16 + rr] = b2p[f];
    }
  }
}

// ---------------------------------------------------------------------------
// Kernel 2: parallel cost build. 16 slices x 16 batches = 256 blocks.
// Internal reduction in double; final cost cast to fp32 for the solver.
// ---------------------------------------------------------------------------
template <int NSPLIT>
__global__ __launch_bounds__(256) void reduce_cost(const float* __restrict__ ws,
                                                   float* __restrict__ costg) {
  const int slice = blockIdx.x;  // 0..15
  const int b = blockIdx.y;
  const int tid = threadIdx.x;
  __shared__ double a2s[4], b2s[64];
  const size_t pa2 = (size_t)NB * NSPLIT * 4096;
  const size_t pb2 = pa2 + (size_t)NB * NSPLIT * 64;

  if (tid < 64) {
    double s = 0.0;
    for (int sp = 0; sp < NSPLIT; ++sp)
      s += (double)ws[pb2 + (size_t)(b * NSPLIT + sp) * 64 + tid];
    b2s[tid] = s;
  } else if (tid < 68) {
    const int r = slice * 4 + (tid - 64);
    double s = 0.0;
    for (int sp = 0; sp < NSPLIT; ++sp)
      s += (double)ws[pa2 + (size_t)(b * NSPLIT + sp) * 64 + r];
    a2s[tid - 64] = s;
  }

  const int elem = slice * 256 + tid;   // 0..4095
  double acc = 0.0;
  for (int sp = 0; sp < NSPLIT; ++sp)
    acc += (double)ws[(size_t)(b * NSPLIT + sp) * 4096 + elem];
  __syncthreads();

  const int ii = tid >> 6;              // row within slice
  const int j = tid & 63;
  const double c2 = a2s[ii] + b2s[j] - 2.0 * acc;
  costg[(size_t)b * 4096 + elem] = (float)sqrt(c2 > 0.0 ? c2 : 0.0);
}

// ---------------------------------------------------------------------------
// Kernel 3: pure solver, fp32 (r10/r16 proven). 16 blocks x 1 wave.
// Col-reduction init + greedy, JV reduction transfer, ARR with fused
// min/2nd-min DPP reduce (cap 8, 2 passes), register Dijkstra.
// ---------------------------------------------------------------------------
__device__ __forceinline__ float readlane_f(float x, int lane) {
  return __int_as_float(__builtin_amdgcn_readlane(__float_as_int(x), lane));
}

template <int CTRL, int RMASK>
__device__ __forceinline__ float dpp_mov_inf(float k) {
  // invalid lanes read old = +inf (min identity)
  return __int_as_float(__builtin_amdgcn_update_dpp(
      0x7F800000, __float_as_int(k), CTRL, RMASK, 0xf, false));
}

template <int CTRL, int RMASK>
__device__ __forceinline__ float dpp_minf_step(float k) {
  return fminf(dpp_mov_inf<CTRL, RMASK>(k), k);
}
// 64-lane fp32 min, uniform result
__device__ __forceinline__ float dpp_minf(float k) {
  k = dpp_minf_step<0x111, 0xf>(k);   // row_shr:1
  k = dpp_minf_step<0x112, 0xf>(k);   // row_shr:2
  k = dpp_minf_step<0x114, 0xf>(k);   // row_shr:4
  k = dpp_minf_step<0x118, 0xf>(k);   // row_shr:8
  k = dpp_minf_step<0x142, 0xa>(k);   // row_bcast:15
  k = dpp_minf_step<0x143, 0xc>(k);   // row_bcast:31
  return readlane_f(k, 63);
}

template <int CTRL, int RMASK>
__device__ __forceinline__ void dpp_min2_step(float& m1, float& m2) {
  const float o1 = dpp_mov_inf<CTRL, RMASK>(m1);
  const float o2 = dpp_mov_inf<CTRL, RMASK>(m2);
  const float lo = fminf(m1, o1);
  const float hi = fmaxf(m1, o1);
  m2 = fminf(fminf(m2, o2), hi);
  m1 = lo;
}
// 64-lane fused (min, 2nd-min-multiset), uniform result
__device__ __forceinline__ float2 dpp_min2f(float x) {
  float m1 = x, m2 = __int_as_float(0x7F800000);
  dpp_min2_step<0x111, 0xf>(m1, m2);   // row_shr:1
  dpp_min2_step<0x112, 0xf>(m1, m2);   // row_shr:2
  dpp_min2_step<0x114, 0xf>(m1, m2);   // row_shr:4
  dpp_min2_step<0x118, 0xf>(m1, m2);   // row_shr:8
  dpp_min2_step<0x142, 0xa>(m1, m2);   // row_bcast:15
  dpp_min2_step<0x143, 0xc>(m1, m2);   // row_bcast:31
  return make_float2(readlane_f(m1, 63), readlane_f(m2, 63));
}

__global__ __launch_bounds__(64) void lsa_solve(const float* __restrict__ costg,
                                                int* __restrict__ out) {
  const int b = blockIdx.x;
  __shared__ float costd[64 * 64];
  const int tid = threadIdx.x;

  for (int e = tid; e < 4096; e += 64)
    costd[e] = costg[(size_t)b * 4096 + e];
  __syncthreads();

  const int l = tid;                 // lane l <-> column l+1, row l+1
  const float INFF = 1e30f;

  // ---- column reduction: v[j] = min_i c[i,j]; greedy tight matching, u=0
  float cmin = costd[l];
  int cargmin = 0;
#pragma unroll 8
  for (int r = 1; r < 64; ++r) {
    const float cv = costd[r * 64 + l];
    if (cv < cmin) { cmin = cv; cargmin = r; }
  }
  float v_l = cmin;
  float u_l = 0.0f;
  int p_l = 0;                       // row matched to column l+1 (0 = free)
  int colof_l = 0;                   // column matched to row l+1 (0 = free)
  unsigned long long rowused = 0ULL;
  for (int j = 0; j < 64; ++j) {
    const int rj = __builtin_amdgcn_readlane(cargmin, j);
    if (!((rowused >> rj) & 1ULL)) {
      rowused |= 1ULL << rj;
      if (l == j) p_l = rj + 1;
      if (l == rj) colof_l = j + 1;
    }
  }
  unsigned long long freemask = ~rowused;  // bit r-1 = row r unassigned

  // ---- JV reduction transfer
  {
    unsigned long long rm = rowused;
    while (rm) {
      const int ri = __ffsll(rm) - 1;          // 0-indexed matched row
      rm &= rm - 1;
      const int j1 = __builtin_amdgcn_readlane(colof_l, ri) - 1;  // its col
      const float red = (l == j1) ? INFF : (costd[ri * 64 + l] - v_l);
      const float rmin = dpp_minf(red);
      if (l == ri) u_l = rmin;
      if (l == j1) v_l -= rmin;
    }
  }

  // ---- Augmenting Row Reduction (JV), chain cap 8, 2 passes, fused 2-min
  for (int pass = 0; pass < 2; ++pass) {
    unsigned long long m = freemask;
    while (m) {
      int ir = __ffsll(m);           // 1-indexed free row
      m &= m - 1;
      for (int chain = 0; chain < 8; ++chain) {
        if (!((freemask >> (ir - 1)) & 1ULL)) break;
        const float uir = readlane_f(u_l, ir - 1);
        const float curx = costd[(ir - 1) * 64 + l] - uir - v_l;
        const float2 mm = dpp_min2f(curx);
        const float u1 = mm.x;
        const float u2 = mm.y;       // == min over j != j1 (incl. tie case)
        const int j1 = __ffsll(__ballot(curx == u1)) - 1;
        if (l == ir - 1) u_l = uir + u2;
        const bool strict = (u1 < u2);
        if (strict && l == j1) v_l -= (u2 - u1);
        const int k = __builtin_amdgcn_readlane(p_l, j1);  // occupant of col j1
        if (strict || k == 0) {
          if (l == j1) p_l = ir;
          if (l == ir - 1) colof_l = j1 + 1;
          freemask &= ~(1ULL << (ir - 1));
          if (k != 0) {
            if (l == k - 1) colof_l = 0;
            freemask |= 1ULL << (k - 1);
            if (strict) { ir = k; continue; }  // retry kicked row
          }
          break;
        } else {
          break;                     // tie & occupied: leave for Dijkstra
        }
      }
    }
  }

  // ---- shortest augmenting path for remaining free rows
  for (int i_row = 1; i_row <= 64; ++i_row) {
    if (!((freemask >> (i_row - 1)) & 1ULL)) continue;
    float minv = INFF;
    int way_l = 0;
    bool used = false;
    int j0 = 0;
    const bool irow_hit = (l + 1 == i_row);

    while (true) {
      const int i0 = (j0 == 0) ? i_row : __builtin_amdgcn_readlane(p_l, j0 - 1);
      if (i0 == 0) break;
      if (j0 > 0 && l == j0 - 1) used = true;
      // off the reduce chain: depends only on `used` and colof
      const unsigned long long um = __ballot(used);
      const bool addu = irow_hit ||
                        (colof_l != 0 && ((um >> (colof_l - 1)) & 1ULL));
      const float ui0 = readlane_f(u_l, i0 - 1);
      const float cur = costd[(i0 - 1) * 64 + l] - ui0 - v_l;
      if (!used && cur < minv) { minv = cur; way_l = j0; }
      const float cand = used ? INFF : minv;

      const float delta = dpp_minf(cand);
      const int jmin = __ffsll(__ballot(cand == delta)) - 1;

      if (used) v_l -= delta; else minv -= delta;
      if (addu) u_l += delta;
      j0 = jmin + 1;
    }

    while (j0 != 0) {
      const int j1 = __builtin_amdgcn_readlane(way_l, j0 - 1);
      const int pj1 = (j1 == 0) ? i_row : __builtin_amdgcn_readlane(p_l, j1 - 1);
      if (l == j0 - 1) p_l = pj1;
      if (l == pj1 - 1) colof_l = j0;
      j0 = j1;
    }
  }

  out[b * NK + l] = l;                       // inds  (arange)
  out[NB * NK + b * NK + l] = colof_l - 1;   // inds2 (col of row l+1)
}

extern "C" void kernel_launch(void* const* d_in, const int* in_sizes, int n_in,
                              void* d_out, int out_size, void* d_ws, size_t ws_size,
                              hipStream_t stream) {
  const float* A = (const float*)d_in[0];   // outputs [16,64,50176] fp32
  const float* B = (const float*)d_in[1];   // targets [16,64,50176] fp32
  float* ws = (float*)d_ws;
  int* out = (int*)d_out;                   // 2048 int32: [inds | inds2]

  // partials: NB*KSPLIT*(4096+128) floats ≈ 17.3 MB; cost floats appended.
  const size_t fpart = (size_t)NB * KSPLIT * 4224;
  float* costg = ws + fpart;

  gemm_partial<<<dim3(16, NB), 256, 0, stream>>>(A, B, ws);
  reduce_cost<KSPLIT><<<dim3(16, NB), 256, 0, stream>>>(ws, costg);
  lsa_solve<<<NB, 64, 0, stream>>>(costg, out);
}